// Round 2
// baseline (487.641 us; speedup 1.0000x reference)
//
#include <hip/hip_runtime.h>
#include <stdint.h>

typedef unsigned short u16;
typedef unsigned int u32;
typedef __bf16 bf16x8 __attribute__((ext_vector_type(8)));
typedef float f32x4 __attribute__((ext_vector_type(4)));

// ---------- bf16 helpers (raw-bits; OCP bf16 = fp32 upper 16, RNE) ----------
__device__ __forceinline__ float bf2f(u16 u) {
  u32 v = ((u32)u) << 16;
  return __builtin_bit_cast(float, v);
}
__device__ __forceinline__ u16 f2bf(float f) {
  u32 u = __builtin_bit_cast(u32, f);
  u32 r = u + 0x7fffu + ((u >> 16) & 1u);
  return (u16)(r >> 16);
}

__device__ __forceinline__ float block_sum4(float v, float* red, int t) {
#pragma unroll
  for (int o = 32; o; o >>= 1) v += __shfl_xor(v, o, 64);
  if ((t & 63) == 0) red[t >> 6] = v;
  __syncthreads();
  float r = red[0] + red[1] + red[2] + red[3];
  __syncthreads();
  return r;
}

// --------- dtype probe: bf16 buffers have ~100% sane exponents; fp32 read as
// --------- u16 pairs has ~62% (mantissa halves are random bits). -----------
__global__ void detect_dtype(const u16* __restrict__ X, int* __restrict__ flag) {
  int t = threadIdx.x;  // 64 threads
  int sane = 0;
#pragma unroll
  for (int i = 0; i < 8; ++i) {
    u16 u = X[t * 8 + i];
    int e = (u >> 7) & 0xff;
    if (u == 0 || u == 0x8000 || (e >= 0x61 && e <= 0x9e)) sane++;
  }
#pragma unroll
  for (int o = 32; o; o >>= 1) sane += __shfl_xor(sane, o, 64);
  if (t == 0) *flag = (sane < 448) ? 1 : 0;  // 1 = fp32 inputs
}

// ---- canonicalize: copy (bf16 world) or downconvert (fp32 world) to bf16 ---
__global__ __launch_bounds__(256) void cvt_bf16(
    const void* __restrict__ src, u16* __restrict__ dst, int n,
    const int* __restrict__ flag) {
  int i = blockIdx.x * 256 + threadIdx.x;
  int stride = gridDim.x * 256;
  if (*flag) {
    const float* s = (const float*)src;
    for (; i < n; i += stride) dst[i] = f2bf(s[i]);
  } else {
    const u16* s = (const u16*)src;
    for (; i < n; i += stride) dst[i] = s[i];
  }
}

// ---------------- LayerNorm over bf16 rows (D=1024), out bf16 ----------------
__global__ __launch_bounds__(256) void ln_rows_bf16(
    const u16* __restrict__ X, const u16* __restrict__ G,
    const u16* __restrict__ Bt, u16* __restrict__ O) {
  __shared__ float red[4];
  const int D = 1024;
  int row = blockIdx.x, t = threadIdx.x;
  const u16* x = X + (size_t)row * D + t * 4;
  u32 r0 = *(const u32*)(x);
  u32 r1 = *(const u32*)(x + 2);
  float v[4] = {bf2f(r0 & 0xffff), bf2f(r0 >> 16), bf2f(r1 & 0xffff), bf2f(r1 >> 16)};
  float s = v[0] + v[1] + v[2] + v[3];
  s = block_sum4(s, red, t);
  float mean = s * (1.f / 1024.f);
  float q = 0.f;
#pragma unroll
  for (int i = 0; i < 4; ++i) { float d = v[i] - mean; q += d * d; }
  q = block_sum4(q, red, t);
  float rstd = rsqrtf(q * (1.f / 1024.f) + 1e-5f);
  u32 g0 = *(const u32*)(G + t * 4), g1 = *(const u32*)(G + t * 4 + 2);
  u32 b0 = *(const u32*)(Bt + t * 4), b1 = *(const u32*)(Bt + t * 4 + 2);
  float gg[4] = {bf2f(g0 & 0xffff), bf2f(g0 >> 16), bf2f(g1 & 0xffff), bf2f(g1 >> 16)};
  float bb[4] = {bf2f(b0 & 0xffff), bf2f(b0 >> 16), bf2f(b1 & 0xffff), bf2f(b1 >> 16)};
  u16 o[4];
#pragma unroll
  for (int i = 0; i < 4; ++i) o[i] = f2bf((v[i] - mean) * rstd * gg[i] + bb[i]);
  u32* op = (u32*)(O + (size_t)row * D + t * 4);
  op[0] = (u32)o[0] | ((u32)o[1] << 16);
  op[1] = (u32)o[2] | ((u32)o[3] << 16);
}

// -------- residual add (x0[b] + proj_out[row]) + LN2; cls_pre kept fp32 ------
__global__ __launch_bounds__(256) void resid_ln(
    const u16* __restrict__ X, const u16* __restrict__ P,
    const u16* __restrict__ G, const u16* __restrict__ Bt,
    float* __restrict__ CLS, u16* __restrict__ H2) {
  __shared__ float red[4];
  const int D = 1024;
  int row = blockIdx.x, t = threadIdx.x;
  int bi = (row < 128) ? (row >> 4) : (row - 128);
  const u16* x = X + (size_t)bi * D + t * 4;
  const u16* p = P + (size_t)row * D + t * 4;
  u32 r0 = *(const u32*)(x), r1 = *(const u32*)(x + 2);
  u32 q0 = *(const u32*)(p), q1 = *(const u32*)(p + 2);
  float v[4];
  v[0] = bf2f(r0 & 0xffff) + bf2f(q0 & 0xffff);
  v[1] = bf2f(r0 >> 16) + bf2f(q0 >> 16);
  v[2] = bf2f(r1 & 0xffff) + bf2f(q1 & 0xffff);
  v[3] = bf2f(r1 >> 16) + bf2f(q1 >> 16);
  float* cp = CLS + (size_t)row * D + t * 4;
#pragma unroll
  for (int i = 0; i < 4; ++i) cp[i] = v[i];
  float s = v[0] + v[1] + v[2] + v[3];
  s = block_sum4(s, red, t);
  float mean = s * (1.f / 1024.f);
  float q = 0.f;
#pragma unroll
  for (int i = 0; i < 4; ++i) { float d = v[i] - mean; q += d * d; }
  q = block_sum4(q, red, t);
  float rstd = rsqrtf(q * (1.f / 1024.f) + 1e-5f);
  u32 g0 = *(const u32*)(G + t * 4), g1 = *(const u32*)(G + t * 4 + 2);
  u32 b0 = *(const u32*)(Bt + t * 4), b1 = *(const u32*)(Bt + t * 4 + 2);
  float gg[4] = {bf2f(g0 & 0xffff), bf2f(g0 >> 16), bf2f(g1 & 0xffff), bf2f(g1 >> 16)};
  float bb[4] = {bf2f(b0 & 0xffff), bf2f(b0 >> 16), bf2f(b1 & 0xffff), bf2f(b1 >> 16)};
  u16 o[4];
#pragma unroll
  for (int i = 0; i < 4; ++i) o[i] = f2bf((v[i] - mean) * rstd * gg[i] + bb[i]);
  u32* op = (u32*)(H2 + (size_t)row * D + t * 4);
  op[0] = (u32)o[0] | ((u32)o[1] << 16);
  op[1] = (u32)o[2] | ((u32)o[3] << 16);
}

// ---------------- generic bf16 GEMM: C[m,n] = sum_k A[m,k]*W[n,k] ------------
// mode 0: +bias; 1: +bias,QuickGELU; 2: +bias,+resid(fp32), dtype per oflag
#define BM 64
#define BN 64
#define BKT 64
#define LDT 72

__global__ __launch_bounds__(256) void gemm_bt(
    const u16* __restrict__ A, int lda, const u16* __restrict__ W, int ldw,
    const u16* __restrict__ bias, void* __restrict__ Cv, int ldc,
    const float* __restrict__ resid, const int* __restrict__ oflag,
    int M, int N, int K, int mode) {
  __shared__ u16 As[BM * LDT];
  __shared__ u16 Bs[BN * LDT];
  int t = threadIdx.x;
  int bm = blockIdx.x * BM, bn = blockIdx.y * BN;
  int lane = t & 63, wv = t >> 6;
  f32x4 acc[4] = {};
  int srow = t >> 3;
  int scol = (t & 7) * 8;

  for (int k0 = 0; k0 < K; k0 += BKT) {
    __syncthreads();
#pragma unroll
    for (int rr = 0; rr < 2; ++rr) {
      int r = srow + rr * 32;
      int gm = bm + r;
      uint4 da = {0, 0, 0, 0};
      if (gm < M) da = *(const uint4*)(A + (size_t)gm * lda + k0 + scol);
      *(uint4*)(&As[r * LDT + scol]) = da;
      int gn = bn + r;
      uint4 dw = {0, 0, 0, 0};
      if (gn < N) dw = *(const uint4*)(W + (size_t)gn * ldw + k0 + scol);
      *(uint4*)(&Bs[r * LDT + scol]) = dw;
    }
    __syncthreads();
    int quad = lane >> 4, rlow = lane & 15;
#pragma unroll
    for (int kk = 0; kk < BKT; kk += 32) {
      bf16x8 a = *(const bf16x8*)(&As[(wv * 16 + rlow) * LDT + kk + quad * 8]);
#pragma unroll
      for (int j = 0; j < 4; ++j) {
        bf16x8 b = *(const bf16x8*)(&Bs[(j * 16 + rlow) * LDT + kk + quad * 8]);
        acc[j] = __builtin_amdgcn_mfma_f32_16x16x32_bf16(a, b, acc[j], 0, 0, 0);
      }
    }
  }
  int quad = lane >> 4, cidx = lane & 15;
  int fp32out = (mode == 2 && oflag && *oflag);
#pragma unroll
  for (int j = 0; j < 4; ++j) {
    int gn = bn + j * 16 + cidx;
    float bv = bf2f(bias[gn]);
#pragma unroll
    for (int r = 0; r < 4; ++r) {
      int gm = bm + wv * 16 + quad * 4 + r;
      if (gm < M && gn < N) {
        float v = acc[j][r] + bv;
        if (mode == 1) v = v / (1.f + __expf(-1.702f * v));
        if (mode == 2) v += resid[(size_t)gm * ldc + gn];
        size_t idx = (size_t)gm * ldc + gn;
        if (fp32out) ((float*)Cv)[idx] = v;
        else ((u16*)Cv)[idx] = f2bf(v);
      }
    }
  }
}

// --- qw[b,h,:] = sum_n (q0[b,h*64+n]/8) * Wk[h*64+n,:]; c0 = qs . bk --------
__global__ __launch_bounds__(256) void qw_build(
    const u16* __restrict__ Q0, const u16* __restrict__ WK,
    const u16* __restrict__ BK, u16* __restrict__ QW, float* __restrict__ C0) {
  int bh = blockIdx.x, b = bh >> 4, h = bh & 15;
  __shared__ float qs[64];
  int t = threadIdx.x;
  if (t < 64) qs[t] = bf2f(Q0[b * 1024 + h * 64 + t]) * 0.125f;
  __syncthreads();
  float acc[4] = {0.f, 0.f, 0.f, 0.f};
  int d0 = t * 4;
  for (int n = 0; n < 64; ++n) {
    const u16* wr = WK + (size_t)(h * 64 + n) * 1024 + d0;
    u32 w0 = *(const u32*)wr;
    u32 w1 = *(const u32*)(wr + 2);
    float q = qs[n];
    acc[0] += q * bf2f(w0 & 0xffff);
    acc[1] += q * bf2f(w0 >> 16);
    acc[2] += q * bf2f(w1 & 0xffff);
    acc[3] += q * bf2f(w1 >> 16);
  }
  u16 o[4];
#pragma unroll
  for (int i = 0; i < 4; ++i) o[i] = f2bf(acc[i]);
  u32* op = (u32*)(QW + (size_t)bh * 1024 + d0);
  op[0] = (u32)o[0] | ((u32)o[1] << 16);
  op[1] = (u32)o[2] | ((u32)o[3] << 16);
  if (t == 0) {
    float c = 0.f;
    for (int n = 0; n < 64; ++n) c += qs[n] * bf2f(BK[h * 64 + n]);
    C0[bh] = c;
  }
}

// ------ attn[b,h,s] = h[s,b,:] . qw[b,h,:] + c0[b,h]  (fp32 out) ------------
#define HLD 516  // u32 row stride: %32 == 4 -> 2-way LDS conflict only
__global__ __launch_bounds__(256) void attn_dot(
    const u16* __restrict__ H, const u16* __restrict__ QW,
    const float* __restrict__ C0, float* __restrict__ ATT) {
  __shared__ u32 Hs[16 * HLD];
  int b = blockIdx.y, s0 = blockIdx.x * 16, t = threadIdx.x;
  for (int idx = t; idx < 16 * 512; idx += 256) {
    int row = idx >> 9, col = idx & 511;
    int s = s0 + row;
    u32 v = 0;
    if (s < 577) v = *(const u32*)(H + ((size_t)(s * 8 + b) << 10) + col * 2);
    Hs[row * HLD + col] = v;
  }
  __syncthreads();
  int si = t & 15, hh = t >> 4;
  int s = s0 + si;
  if (s < 577) {
    const u32* hr = &Hs[si * HLD];
    const u16* qr = QW + (size_t)(b * 16 + hh) * 1024;
    float acc = 0.f;
    for (int d = 0; d < 512; ++d) {
      u32 hv = hr[d];
      u32 qv = *(const u32*)(qr + d * 2);
      acc += bf2f(hv & 0xffff) * bf2f(qv & 0xffff) + bf2f(hv >> 16) * bf2f(qv >> 16);
    }
    ATT[(size_t)(b * 16 + hh) * 577 + s] = acc + C0[b * 16 + hh];
  }
}

// ---- softmax(attn [+mask]) then PV: one block per (b, x, h); x==16 = plain --
__global__ __launch_bounds__(256) void softmax_pv(
    const float* __restrict__ ATT, const u16* __restrict__ MASK,
    const u16* __restrict__ V, u16* __restrict__ AO) {
  const int S = 577;
  int blk = blockIdx.x;
  int b = blk / 272, rem = blk % 272;
  int x = rem >> 4, h = rem & 15;
  __shared__ float p[S];
  __shared__ float redm[4];
  __shared__ float reds[4];
  __shared__ float partial[256];
  int t = threadIdx.x, lane = t & 63, wv = t >> 6;
  const float* arow = ATT + (size_t)(b * 16 + h) * S;
  float lmax = -3e38f;
  for (int s = t; s < S; s += 256) {
    float v = arow[s];
    if (x < 16) v += bf2f(MASK[(size_t)((b * 16 + x) * 16 + h) * S + s]);
    p[s] = v;
    lmax = fmaxf(lmax, v);
  }
#pragma unroll
  for (int o = 32; o; o >>= 1) lmax = fmaxf(lmax, __shfl_xor(lmax, o, 64));
  if (lane == 0) redm[wv] = lmax;
  __syncthreads();
  float m = fmaxf(fmaxf(redm[0], redm[1]), fmaxf(redm[2], redm[3]));
  float lsum = 0.f;
  for (int s = t; s < S; s += 256) {
    float e = __expf(p[s] - m);
    p[s] = e;
    lsum += e;
  }
#pragma unroll
  for (int o = 32; o; o >>= 1) lsum += __shfl_xor(lsum, o, 64);
  if (lane == 0) reds[wv] = lsum;
  __syncthreads();
  float inv = 1.f / (reds[0] + reds[1] + reds[2] + reds[3]);
  float acc = 0.f;
  const u16* vb = V + h * 64 + lane;
  for (int s = wv; s < S; s += 4) acc += p[s] * bf2f(vb[(size_t)(s * 8 + b) << 10]);
  partial[t] = acc;
  __syncthreads();
  if (t < 64) {
    float r = (partial[t] + partial[t + 64] + partial[t + 128] + partial[t + 192]) * inv;
    int row = (x < 16) ? (b * 16 + x) : (128 + b);
    AO[(size_t)row * 1024 + h * 64 + t] = f2bf(r);
  }
}

// ----------------------------------------------------------------------------
extern "C" void kernel_launch(void* const* d_in, const int* in_sizes, int n_in,
                              void* d_out, int out_size, void* d_ws, size_t ws_size,
                              hipStream_t stream) {
  const int SB = 577 * 8;
  char* base = (char*)d_ws;
  size_t off = 0;
  auto alloc = [&](size_t bytes) {
    char* p = base + off;
    off += (bytes + 255) & ~(size_t)255;
    return p;
  };
  int* flag     = (int*)alloc(256);
  u16* h        = (u16*)alloc((size_t)SB * 1024 * 2);
  u16* v        = (u16*)alloc((size_t)SB * 1024 * 2);
  u16* q0       = (u16*)alloc(8 * 1024 * 2);
  u16* qw       = (u16*)alloc(128 * 1024 * 2);
  float* c0     = (float*)alloc(128 * 4);
  float* attn   = (float*)alloc(128 * 577 * 4);
  u16* attn_out = (u16*)alloc(136 * 1024 * 2);
  u16* proj_out = (u16*)alloc(136 * 1024 * 2);
  float* clspre = (float*)alloc(136 * 1024 * 4);
  u16* h2       = (u16*)alloc(136 * 1024 * 2);
  u16* hfc      = (u16*)alloc(136 * 4096 * 2);
  size_t pipe_need = off;

  // canonical bf16 copies of float inputs (indices 0,1,5..16)
  static const int cidx[14] = {0, 1, 5, 6, 7, 8, 9, 10, 11, 12, 13, 14, 15, 16};
  size_t canon_bytes = 0;
  for (int i = 0; i < 14; ++i)
    canon_bytes += (((size_t)in_sizes[cidx[i]] * 2) + 255) & ~(size_t)255;
  bool fat = (ws_size >= pipe_need + canon_bytes);

  detect_dtype<<<1, 64, 0, stream>>>((const u16*)d_in[0], flag);

  const u16* cp[17];
  for (int i = 0; i < 17; ++i) cp[i] = (const u16*)d_in[i];
  if (fat) {
    for (int i = 0; i < 14; ++i) {
      int k = cidx[i];
      int n = in_sizes[k];
      u16* dst = (u16*)alloc((size_t)n * 2);
      int blocks = (n + 256 * 8 - 1) / (256 * 8);
      if (blocks > 1024) blocks = 1024;
      if (blocks < 1) blocks = 1;
      cvt_bf16<<<blocks, 256, 0, stream>>>(d_in[k], dst, n, flag);
      cp[k] = dst;
    }
  }
  const u16* x      = cp[0];
  const u16* mask   = cp[1];
  const u16* in_w   = cp[5];
  const u16* in_b   = cp[6];
  const u16* out_w  = cp[7];
  const u16* out_b  = cp[8];
  const u16* ln1_g  = cp[9];
  const u16* ln1_b  = cp[10];
  const u16* ln2_g  = cp[11];
  const u16* ln2_b  = cp[12];
  const u16* fc_w   = cp[13];
  const u16* fc_b   = cp[14];
  const u16* proj_w = cp[15];
  const u16* proj_b = cp[16];

  // 1) LN1 over all S*B rows
  ln_rows_bf16<<<SB, 256, 0, stream>>>(x, ln1_g, ln1_b, h);
  // 2) v = h @ Wv^T + bv   (Wv = in_proj_w rows 2048..3071)
  gemm_bt<<<dim3((SB + 63) / 64, 1024 / 64), 256, 0, stream>>>(
      h, 1024, in_w + (size_t)2048 * 1024, 1024, in_b + 2048, v, 1024,
      nullptr, nullptr, SB, 1024, 1024, 0);
  // 3) q0 = h[s=0 rows 0..7] @ Wq^T + bq
  gemm_bt<<<dim3(1, 1024 / 64), 256, 0, stream>>>(
      h, 1024, in_w, 1024, in_b, q0, 1024, nullptr, nullptr, 8, 1024, 1024, 0);
  // 4) qw = (q0/8) . Wk  (k-projection pulled through the query)
  qw_build<<<128, 256, 0, stream>>>(q0, in_w + (size_t)1024 * 1024,
                                    in_b + 1024, qw, c0);
  // 5) attn logits from h . qw
  attn_dot<<<dim3(37, 8), 256, 0, stream>>>(h, qw, c0, attn);
  // 6) softmax(+mask) + PV
  softmax_pv<<<8 * 17 * 16, 256, 0, stream>>>(attn, mask, v, attn_out);
  // 7) out-projection
  gemm_bt<<<dim3(3, 1024 / 64), 256, 0, stream>>>(
      attn_out, 1024, out_w, 1024, out_b, proj_out, 1024, nullptr, nullptr,
      136, 1024, 1024, 0);
  // 8) residual + LN2
  resid_ln<<<136, 256, 0, stream>>>(x, proj_out, ln2_g, ln2_b, clspre, h2);
  // 9) fc + QuickGELU
  gemm_bt<<<dim3(3, 4096 / 64), 256, 0, stream>>>(
      h2, 1024, fc_w, 1024, fc_b, hfc, 4096, nullptr, nullptr, 136, 4096, 1024, 1);
  // 10) proj + bias + residual -> d_out (dtype chosen by flag)
  gemm_bt<<<dim3(3, 1024 / 64), 256, 0, stream>>>(
      hfc, 4096, proj_w, 4096, proj_b, d_out, 1024, clspre, flag,
      136, 1024, 4096, 2);

  (void)n_in; (void)out_size;
}

// Round 6
// 331.916 us; speedup vs baseline: 1.4692x; 1.4692x over previous
//
#include <hip/hip_runtime.h>
#include <stdint.h>

typedef unsigned short u16;
typedef unsigned int u32;
typedef __bf16 bf16x8 __attribute__((ext_vector_type(8)));
typedef float f32x4 __attribute__((ext_vector_type(4)));

// ---------- bf16 helpers ----------
__device__ __forceinline__ float bf2f(u16 u) {
  u32 v = ((u32)u) << 16;
  return __builtin_bit_cast(float, v);
}
__device__ __forceinline__ u16 f2bf(float f) {
  u32 u = __builtin_bit_cast(u32, f);
  u32 r = u + 0x7fffu + ((u >> 16) & 1u);
  return (u16)(r >> 16);
}

__device__ __forceinline__ float block_sum4(float v, float* red, int t) {
#pragma unroll
  for (int o = 32; o; o >>= 1) v += __shfl_xor(v, o, 64);
  if ((t & 63) == 0) red[t >> 6] = v;
  __syncthreads();
  float r = red[0] + red[1] + red[2] + red[3];
  __syncthreads();
  return r;
}

// ---------------- fp32 -> bf16 conversion, 4 elems/thread -------------------
__global__ __launch_bounds__(256) void cvt_f32_bf16(
    const float* __restrict__ S, u16* __restrict__ D, int n) {
  int i = (blockIdx.x * 256 + threadIdx.x) * 4;
  if (i < n) {
    float4 f = *(const float4*)(S + i);
    u32 lo = (u32)f2bf(f.x) | ((u32)f2bf(f.y) << 16);
    u32 hi = (u32)f2bf(f.z) | ((u32)f2bf(f.w) << 16);
    uint2 val = {lo, hi};
    *(uint2*)(D + i) = val;
  }
}

// ---------------- LayerNorm over fp32 rows (D=1024), out bf16 ----------------
__global__ __launch_bounds__(256) void ln_rows_f32(
    const float* __restrict__ X, const float* __restrict__ G,
    const float* __restrict__ Bt, u16* __restrict__ O) {
  __shared__ float red[4];
  int row = blockIdx.x, t = threadIdx.x;
  float4 xv = *(const float4*)(X + (size_t)row * 1024 + t * 4);
  float v[4] = {xv.x, xv.y, xv.z, xv.w};
  float s = v[0] + v[1] + v[2] + v[3];
  s = block_sum4(s, red, t);
  float mean = s * (1.f / 1024.f);
  float q = 0.f;
#pragma unroll
  for (int i = 0; i < 4; ++i) { float d = v[i] - mean; q += d * d; }
  q = block_sum4(q, red, t);
  float rstd = rsqrtf(q * (1.f / 1024.f) + 1e-5f);
  float4 g = *(const float4*)(G + t * 4);
  float4 b = *(const float4*)(Bt + t * 4);
  float gg[4] = {g.x, g.y, g.z, g.w}, bb[4] = {b.x, b.y, b.z, b.w};
  u16 o[4];
#pragma unroll
  for (int i = 0; i < 4; ++i) o[i] = f2bf((v[i] - mean) * rstd * gg[i] + bb[i]);
  u32* op = (u32*)(O + (size_t)row * 1024 + t * 4);
  op[0] = (u32)o[0] | ((u32)o[1] << 16);
  op[1] = (u32)o[2] | ((u32)o[3] << 16);
}

// ---- residual (x0 fp32 + accO fp32) + LN2; cls_pre fp32, h2 bf16 -----------
__global__ __launch_bounds__(256) void resid_ln_f32(
    const float* __restrict__ X, const float* __restrict__ P,
    const float* __restrict__ G, const float* __restrict__ Bt,
    float* __restrict__ CLS, u16* __restrict__ H2) {
  __shared__ float red[4];
  int row = blockIdx.x, t = threadIdx.x;
  int bi = (row < 128) ? (row >> 4) : (row - 128);
  float4 xv = *(const float4*)(X + (size_t)bi * 1024 + t * 4);   // x[0,b,:]
  float4 pv = *(const float4*)(P + (size_t)row * 1024 + t * 4);
  float v[4] = {xv.x + pv.x, xv.y + pv.y, xv.z + pv.z, xv.w + pv.w};
  float* cp = CLS + (size_t)row * 1024 + t * 4;
#pragma unroll
  for (int i = 0; i < 4; ++i) cp[i] = v[i];
  float s = v[0] + v[1] + v[2] + v[3];
  s = block_sum4(s, red, t);
  float mean = s * (1.f / 1024.f);
  float q = 0.f;
#pragma unroll
  for (int i = 0; i < 4; ++i) { float d = v[i] - mean; q += d * d; }
  q = block_sum4(q, red, t);
  float rstd = rsqrtf(q * (1.f / 1024.f) + 1e-5f);
  float4 g = *(const float4*)(G + t * 4);
  float4 b = *(const float4*)(Bt + t * 4);
  float gg[4] = {g.x, g.y, g.z, g.w}, bb[4] = {b.x, b.y, b.z, b.w};
  u16 o[4];
#pragma unroll
  for (int i = 0; i < 4; ++i) o[i] = f2bf((v[i] - mean) * rstd * gg[i] + bb[i]);
  u32* op = (u32*)(H2 + (size_t)row * 1024 + t * 4);
  op[0] = (u32)o[0] | ((u32)o[1] << 16);
  op[1] = (u32)o[2] | ((u32)o[3] << 16);
}

// ---- 64x64 bf16 GEMM (R2-validated core): C = A @ W^T + bias(fp32) ---------
// mode 0: +bias; mode 1: +bias then QuickGELU. Output bf16.
#define LDT 72
__global__ __launch_bounds__(256) void gemm_bt(
    const u16* __restrict__ A, int lda, const u16* __restrict__ W, int ldw,
    const float* __restrict__ bias, u16* __restrict__ C, int ldc,
    int M, int N, int K, int mode) {
  __shared__ u16 As[64 * LDT];
  __shared__ u16 Bs[64 * LDT];
  int t = threadIdx.x;
  int bm = blockIdx.x * 64, bn = blockIdx.y * 64;
  int lane = t & 63, wv = t >> 6;
  f32x4 acc[4] = {};
  int srow = t >> 3;
  int scol = (t & 7) * 8;

  for (int k0 = 0; k0 < K; k0 += 64) {
    __syncthreads();
#pragma unroll
    for (int rr = 0; rr < 2; ++rr) {
      int r = srow + rr * 32;
      int gm = bm + r;
      uint4 da = {0, 0, 0, 0};
      if (gm < M) da = *(const uint4*)(A + (size_t)gm * lda + k0 + scol);
      *(uint4*)(&As[r * LDT + scol]) = da;
      int gn = bn + r;
      uint4 dw = {0, 0, 0, 0};
      if (gn < N) dw = *(const uint4*)(W + (size_t)gn * ldw + k0 + scol);
      *(uint4*)(&Bs[r * LDT + scol]) = dw;
    }
    __syncthreads();
    int quad = lane >> 4, rlow = lane & 15;
#pragma unroll
    for (int kk = 0; kk < 64; kk += 32) {
      bf16x8 a = *(const bf16x8*)(&As[(wv * 16 + rlow) * LDT + kk + quad * 8]);
#pragma unroll
      for (int j = 0; j < 4; ++j) {
        bf16x8 b = *(const bf16x8*)(&Bs[(j * 16 + rlow) * LDT + kk + quad * 8]);
        acc[j] = __builtin_amdgcn_mfma_f32_16x16x32_bf16(a, b, acc[j], 0, 0, 0);
      }
    }
  }
  int quad = lane >> 4, cidx = lane & 15;
#pragma unroll
  for (int j = 0; j < 4; ++j) {
    int gn = bn + j * 16 + cidx;
    float bv = (gn < N) ? bias[gn] : 0.f;
#pragma unroll
    for (int r = 0; r < 4; ++r) {
      int gm = bm + wv * 16 + quad * 4 + r;
      if (gm < M && gn < N) {
        float v = acc[j][r] + bv;
        if (mode == 1) v = v / (1.f + __expf(-1.702f * v));
        C[(size_t)gm * ldc + gn] = f2bf(v);
      }
    }
  }
}

// ---- split-K partial: ACC[m,n] += sum over K-slice of A[m,k]*W[n,k] --------
__global__ __launch_bounds__(256) void gemm_bt_splitk(
    const u16* __restrict__ A, int lda, const u16* __restrict__ W, int ldw,
    float* __restrict__ ACC, int ldc, int M, int N, int KC) {
  __shared__ u16 As[64 * LDT];
  __shared__ u16 Bs[64 * LDT];
  int t = threadIdx.x;
  int bm = blockIdx.x * 64, bn = blockIdx.y * 64;
  int kbase = blockIdx.z * KC;
  int lane = t & 63, wv = t >> 6;
  f32x4 acc[4] = {};
  int srow = t >> 3;
  int scol = (t & 7) * 8;

  for (int k0 = kbase; k0 < kbase + KC; k0 += 64) {
    __syncthreads();
#pragma unroll
    for (int rr = 0; rr < 2; ++rr) {
      int r = srow + rr * 32;
      int gm = bm + r;
      uint4 da = {0, 0, 0, 0};
      if (gm < M) da = *(const uint4*)(A + (size_t)gm * lda + k0 + scol);
      *(uint4*)(&As[r * LDT + scol]) = da;
      int gn = bn + r;
      uint4 dw = {0, 0, 0, 0};
      if (gn < N) dw = *(const uint4*)(W + (size_t)gn * ldw + k0 + scol);
      *(uint4*)(&Bs[r * LDT + scol]) = dw;
    }
    __syncthreads();
    int quad = lane >> 4, rlow = lane & 15;
#pragma unroll
    for (int kk = 0; kk < 64; kk += 32) {
      bf16x8 a = *(const bf16x8*)(&As[(wv * 16 + rlow) * LDT + kk + quad * 8]);
#pragma unroll
      for (int j = 0; j < 4; ++j) {
        bf16x8 b = *(const bf16x8*)(&Bs[(j * 16 + rlow) * LDT + kk + quad * 8]);
        acc[j] = __builtin_amdgcn_mfma_f32_16x16x32_bf16(a, b, acc[j], 0, 0, 0);
      }
    }
  }
  int quad = lane >> 4, cidx = lane & 15;
#pragma unroll
  for (int j = 0; j < 4; ++j) {
    int gn = bn + j * 16 + cidx;
#pragma unroll
    for (int r = 0; r < 4; ++r) {
      int gm = bm + wv * 16 + quad * 4 + r;
      if (gm < M && gn < N) atomicAdd(&ACC[(size_t)gm * ldc + gn], acc[j][r]);
    }
  }
}

// ---------------- ACC[m,n] = bias[n] (fp32 bias) ----------------------------
__global__ __launch_bounds__(256) void acc_init(
    float* __restrict__ ACC, const float* __restrict__ bias, int nmask, int total) {
  int i = (blockIdx.x * 256 + threadIdx.x) * 4;
  if (i < total) {
#pragma unroll
    for (int k = 0; k < 4; ++k) ACC[i + k] = bias[(i + k) & nmask];
  }
}

// ---------------- QuickGELU on fp32 acc -> bf16 ------------------------------
__global__ __launch_bounds__(256) void gelu_cvt(
    const float* __restrict__ ACC, u16* __restrict__ O, int total) {
  int i = (blockIdx.x * 256 + threadIdx.x) * 4;
  if (i < total) {
#pragma unroll
    for (int k = 0; k < 4; ++k) {
      float v = ACC[i + k];
      O[i + k] = f2bf(v / (1.f + __expf(-1.702f * v)));
    }
  }
}

// ---------------- out(fp32) = accP + clspre ---------------------------------
__global__ __launch_bounds__(256) void final_out(
    const float* __restrict__ ACC, const float* __restrict__ CLS,
    float* __restrict__ O, int total) {
  int i = (blockIdx.x * 256 + threadIdx.x) * 4;
  if (i < total) {
#pragma unroll
    for (int k = 0; k < 4; ++k) O[i + k] = ACC[i + k] + CLS[i + k];
  }
}

// --- qw[b,h,:] = sum_n (q0[b,h*64+n]/8)*Wk[h*64+n,:]; c0 = qs . bk ----------
// Q0 = fp32 accumulator from q-projection; WK,BK raw fp32 weights.
__global__ __launch_bounds__(256) void qw_build(
    const float* __restrict__ Q0, const float* __restrict__ WK,
    const float* __restrict__ BK, u16* __restrict__ QW, float* __restrict__ C0) {
  int bh = blockIdx.x, b = bh >> 4, h = bh & 15;
  __shared__ float qs[64];
  int t = threadIdx.x;
  if (t < 64) qs[t] = Q0[b * 1024 + h * 64 + t] * 0.125f;
  __syncthreads();
  float acc[4] = {0.f, 0.f, 0.f, 0.f};
  int d0 = t * 4;
  for (int n = 0; n < 64; ++n) {
    float4 w = *(const float4*)(WK + (size_t)(h * 64 + n) * 1024 + d0);
    float q = qs[n];
    acc[0] += q * w.x;
    acc[1] += q * w.y;
    acc[2] += q * w.z;
    acc[3] += q * w.w;
  }
  u16 o[4];
#pragma unroll
  for (int i = 0; i < 4; ++i) o[i] = f2bf(acc[i]);
  u32* op = (u32*)(QW + (size_t)bh * 1024 + d0);
  op[0] = (u32)o[0] | ((u32)o[1] << 16);
  op[1] = (u32)o[2] | ((u32)o[3] << 16);
  if (t == 0) {
    float c = 0.f;
    for (int n = 0; n < 64; ++n) c += qs[n] * BK[h * 64 + n];
    C0[bh] = c;
  }
}

// ------ attn[b,h,s] = h[s,b,:] . qw[b,h,:] + c0[b,h]  (bf16 in, fp32 out) ---
#define HLD 516
__global__ __launch_bounds__(256) void attn_dot(
    const u16* __restrict__ H, const u16* __restrict__ QW,
    const float* __restrict__ C0, float* __restrict__ ATT) {
  __shared__ u32 Hs[16 * HLD];
  int b = blockIdx.y, s0 = blockIdx.x * 16, t = threadIdx.x;
  for (int idx = t; idx < 16 * 512; idx += 256) {
    int row = idx >> 9, col = idx & 511;
    int s = s0 + row;
    u32 v = 0;
    if (s < 577) v = *(const u32*)(H + ((size_t)(s * 8 + b) << 10) + col * 2);
    Hs[row * HLD + col] = v;
  }
  __syncthreads();
  int si = t & 15, hh = t >> 4;
  int s = s0 + si;
  if (s < 577) {
    const u32* hr = &Hs[si * HLD];
    const u16* qr = QW + (size_t)(b * 16 + hh) * 1024;
    float acc = 0.f;
    for (int d = 0; d < 512; ++d) {
      u32 hv = hr[d];
      u32 qv = *(const u32*)(qr + d * 2);
      acc += bf2f(hv & 0xffff) * bf2f(qv & 0xffff) + bf2f(hv >> 16) * bf2f(qv >> 16);
    }
    ATT[(size_t)(b * 16 + hh) * 577 + s] = acc + C0[b * 16 + hh];
  }
}

// ---- softmax(attn [+mask fp32]) then PV over bf16 V ------------------------
__global__ __launch_bounds__(256) void softmax_pv(
    const float* __restrict__ ATT, const float* __restrict__ MASK,
    const u16* __restrict__ V, u16* __restrict__ AO) {
  const int S = 577;
  int blk = blockIdx.x;
  int b = blk / 272, rem = blk % 272;
  int x = rem >> 4, h = rem & 15;
  __shared__ float p[S];
  __shared__ float redm[4];
  __shared__ float reds[4];
  __shared__ float partial[256];
  int t = threadIdx.x, lane = t & 63, wv = t >> 6;
  const float* arow = ATT + (size_t)(b * 16 + h) * S;
  float lmax = -3e38f;
  for (int s = t; s < S; s += 256) {
    float v = arow[s];
    if (x < 16) v += MASK[(size_t)((b * 16 + x) * 16 + h) * S + s];
    p[s] = v;
    lmax = fmaxf(lmax, v);
  }
#pragma unroll
  for (int o = 32; o; o >>= 1) lmax = fmaxf(lmax, __shfl_xor(lmax, o, 64));
  if (lane == 0) redm[wv] = lmax;
  __syncthreads();
  float m = fmaxf(fmaxf(redm[0], redm[1]), fmaxf(redm[2], redm[3]));
  float lsum = 0.f;
  for (int s = t; s < S; s += 256) {
    float e = __expf(p[s] - m);
    p[s] = e;
    lsum += e;
  }
#pragma unroll
  for (int o = 32; o; o >>= 1) lsum += __shfl_xor(lsum, o, 64);
  if (lane == 0) reds[wv] = lsum;
  __syncthreads();
  float inv = 1.f / (reds[0] + reds[1] + reds[2] + reds[3]);
  float acc = 0.f;
  const u16* vb = V + h * 64 + lane;
  for (int s = wv; s < S; s += 4) acc += p[s] * bf2f(vb[(size_t)(s * 8 + b) << 10]);
  partial[t] = acc;
  __syncthreads();
  if (t < 64) {
    float r = (partial[t] + partial[t + 64] + partial[t + 128] + partial[t + 192]) * inv;
    int row = (x < 16) ? (b * 16 + x) : (128 + b);
    AO[(size_t)row * 1024 + h * 64 + t] = f2bf(r);
  }
}

// ----------------------------------------------------------------------------
extern "C" void kernel_launch(void* const* d_in, const int* in_sizes, int n_in,
                              void* d_out, int out_size, void* d_ws, size_t ws_size,
                              hipStream_t stream) {
  // Inputs are FLOAT32 per the reference (verified: R2 passed only via the
  // fp32->bf16 canonicalize path with fp32 output).
  const float* x      = (const float*)d_in[0];
  const float* mask   = (const float*)d_in[1];
  const float* in_w   = (const float*)d_in[5];
  const float* in_b   = (const float*)d_in[6];
  const float* out_w  = (const float*)d_in[7];
  const float* out_b  = (const float*)d_in[8];
  const float* ln1_g  = (const float*)d_in[9];
  const float* ln1_b  = (const float*)d_in[10];
  const float* ln2_g  = (const float*)d_in[11];
  const float* ln2_b  = (const float*)d_in[12];
  const float* fc_w   = (const float*)d_in[13];
  const float* fc_b   = (const float*)d_in[14];
  const float* proj_w = (const float*)d_in[15];
  const float* proj_b = (const float*)d_in[16];
  float* out = (float*)d_out;

  const int SB = 577 * 8;  // 4616
  char* base = (char*)d_ws;
  size_t off = 0;
  auto alloc = [&](size_t bytes) {
    char* p = base + off;
    off += (bytes + 255) & ~(size_t)255;
    return p;
  };
  // bf16 weight copies (MFMA operands)
  u16* wq_b   = (u16*)alloc((size_t)1024 * 1024 * 2);
  u16* wv_b   = (u16*)alloc((size_t)1024 * 1024 * 2);
  u16* wout_b = (u16*)alloc((size_t)1024 * 1024 * 2);
  u16* wfc_b  = (u16*)alloc((size_t)4096 * 1024 * 2);
  u16* wproj_b= (u16*)alloc((size_t)4096 * 1024 * 2);
  // activations / accumulators
  u16* h        = (u16*)alloc((size_t)SB * 1024 * 2);
  u16* v        = (u16*)alloc((size_t)SB * 1024 * 2);
  float* accQ   = (float*)alloc(8 * 1024 * 4);
  u16* qw       = (u16*)alloc(128 * 1024 * 2);
  float* c0     = (float*)alloc(128 * 4);
  float* attn   = (float*)alloc(128 * 577 * 4);
  u16* attn_out = (u16*)alloc(136 * 1024 * 2);
  float* accO   = (float*)alloc(136 * 1024 * 4);
  float* clspre = (float*)alloc(136 * 1024 * 4);
  u16* h2       = (u16*)alloc(136 * 1024 * 2);
  float* accF   = (float*)alloc((size_t)136 * 4096 * 4);
  u16* hg       = (u16*)alloc((size_t)136 * 4096 * 2);
  float* accP   = (float*)alloc(136 * 1024 * 4);
  // total ~47.4 MB; ws_size >= ~58.6 MB (proven by round 2's fat path)

  // 0) convert the five weight matrices to bf16
  cvt_f32_bf16<<<1024, 256, 0, stream>>>(in_w, wq_b, 1024 * 1024);
  cvt_f32_bf16<<<1024, 256, 0, stream>>>(in_w + (size_t)2048 * 1024, wv_b, 1024 * 1024);
  cvt_f32_bf16<<<1024, 256, 0, stream>>>(out_w, wout_b, 1024 * 1024);
  cvt_f32_bf16<<<4096, 256, 0, stream>>>(fc_w, wfc_b, 4096 * 1024);
  cvt_f32_bf16<<<4096, 256, 0, stream>>>(proj_w, wproj_b, 4096 * 1024);

  // 1) LN1 over all S*B rows (fp32 in, bf16 out)
  ln_rows_f32<<<SB, 256, 0, stream>>>(x, ln1_g, ln1_b, h);
  // 2) v = h @ Wv^T + bv
  gemm_bt<<<dim3((SB + 63) / 64, 16), 256, 0, stream>>>(
      h, 1024, wv_b, 1024, in_b + 2048, v, 1024, SB, 1024, 1024, 0);
  // 3) q0(fp32) = h[rows 0..7] @ Wq^T + bq  via split-K
  acc_init<<<8, 256, 0, stream>>>(accQ, in_b, 1023, 8 * 1024);
  gemm_bt_splitk<<<dim3(1, 16, 8), 256, 0, stream>>>(
      h, 1024, wq_b, 1024, accQ, 1024, 8, 1024, 128);
  // 4) qw = (q0/8) . Wk  (raw fp32 Wk, bk)
  qw_build<<<128, 256, 0, stream>>>(accQ, in_w + (size_t)1024 * 1024,
                                    in_b + 1024, qw, c0);
  // 5) attn logits
  attn_dot<<<dim3(37, 8), 256, 0, stream>>>(h, qw, c0, attn);
  // 6) softmax(+mask) + PV
  softmax_pv<<<8 * 17 * 16, 256, 0, stream>>>(attn, mask, v, attn_out);
  // 7) out-proj via split-K
  acc_init<<<136, 256, 0, stream>>>(accO, out_b, 1023, 136 * 1024);
  gemm_bt_splitk<<<dim3(3, 16, 8), 256, 0, stream>>>(
      attn_out, 1024, wout_b, 1024, accO, 1024, 136, 1024, 128);
  // 8) residual + LN2 (all fp32 inputs)
  resid_ln_f32<<<136, 256, 0, stream>>>(x, accO, ln2_g, ln2_b, clspre, h2);
  // 9) fc via split-K, then QuickGELU
  acc_init<<<544, 256, 0, stream>>>(accF, fc_b, 4095, 136 * 4096);
  gemm_bt_splitk<<<dim3(3, 64, 4), 256, 0, stream>>>(
      h2, 1024, wfc_b, 1024, accF, 4096, 136, 4096, 256);
  gelu_cvt<<<544, 256, 0, stream>>>(accF, hg, 136 * 4096);
  // 10) proj via split-K, then +clspre -> d_out (fp32)
  acc_init<<<136, 256, 0, stream>>>(accP, proj_b, 1023, 136 * 1024);
  gemm_bt_splitk<<<dim3(3, 16, 16), 256, 0, stream>>>(
      hg, 4096, wproj_b, 4096, accP, 1024, 136, 1024, 256);
  final_out<<<136, 256, 0, stream>>>(accP, clspre, out, 136 * 1024);

  (void)in_sizes; (void)n_in; (void)out_size; (void)ws_size;
}

// Round 7
// 282.649 us; speedup vs baseline: 1.7253x; 1.1743x over previous
//
#include <hip/hip_runtime.h>
#include <stdint.h>

typedef unsigned short u16;
typedef unsigned int u32;
typedef __bf16 bf16x8 __attribute__((ext_vector_type(8)));
typedef float f32x4 __attribute__((ext_vector_type(4)));

// ---------- bf16 helpers ----------
__device__ __forceinline__ float bf2f(u16 u) {
  u32 v = ((u32)u) << 16;
  return __builtin_bit_cast(float, v);
}
__device__ __forceinline__ u16 f2bf(float f) {
  u32 u = __builtin_bit_cast(u32, f);
  u32 r = u + 0x7fffu + ((u >> 16) & 1u);
  return (u16)(r >> 16);
}

__device__ __forceinline__ float block_sum4(float v, float* red, int t) {
#pragma unroll
  for (int o = 32; o; o >>= 1) v += __shfl_xor(v, o, 64);
  if ((t & 63) == 0) red[t >> 6] = v;
  __syncthreads();
  float r = red[0] + red[1] + red[2] + red[3];
  __syncthreads();
  return r;
}

// async global->LDS, 16B per lane; LDS dest = wave-uniform base + lane*16
#define GLD16(gp, lp)                                                   \
  __builtin_amdgcn_global_load_lds(                                     \
      (const __attribute__((address_space(1))) void*)(gp),              \
      (__attribute__((address_space(3))) void*)(lp), 16, 0, 0)

// ---------------- fp32 -> bf16 conversion, 4 elems/thread -------------------
__global__ __launch_bounds__(256) void cvt_f32_bf16(
    const float* __restrict__ S, u16* __restrict__ D, int n) {
  int i = (blockIdx.x * 256 + threadIdx.x) * 4;
  if (i < n) {
    float4 f = *(const float4*)(S + i);
    u32 lo = (u32)f2bf(f.x) | ((u32)f2bf(f.y) << 16);
    u32 hi = (u32)f2bf(f.z) | ((u32)f2bf(f.w) << 16);
    uint2 val = {lo, hi};
    *(uint2*)(D + i) = val;
  }
}

// ---------------- LayerNorm over fp32 rows (D=1024), out bf16 ----------------
__global__ __launch_bounds__(256) void ln_rows_f32(
    const float* __restrict__ X, const float* __restrict__ G,
    const float* __restrict__ Bt, u16* __restrict__ O) {
  __shared__ float red[4];
  int row = blockIdx.x, t = threadIdx.x;
  float4 xv = *(const float4*)(X + (size_t)row * 1024 + t * 4);
  float v[4] = {xv.x, xv.y, xv.z, xv.w};
  float s = v[0] + v[1] + v[2] + v[3];
  s = block_sum4(s, red, t);
  float mean = s * (1.f / 1024.f);
  float q = 0.f;
#pragma unroll
  for (int i = 0; i < 4; ++i) { float d = v[i] - mean; q += d * d; }
  q = block_sum4(q, red, t);
  float rstd = rsqrtf(q * (1.f / 1024.f) + 1e-5f);
  float4 g = *(const float4*)(G + t * 4);
  float4 b = *(const float4*)(Bt + t * 4);
  float gg[4] = {g.x, g.y, g.z, g.w}, bb[4] = {b.x, b.y, b.z, b.w};
  u16 o[4];
#pragma unroll
  for (int i = 0; i < 4; ++i) o[i] = f2bf((v[i] - mean) * rstd * gg[i] + bb[i]);
  u32* op = (u32*)(O + (size_t)row * 1024 + t * 4);
  op[0] = (u32)o[0] | ((u32)o[1] << 16);
  op[1] = (u32)o[2] | ((u32)o[3] << 16);
}

// ---- residual (x0 fp32 + accO fp32) + LN2; cls_pre fp32, h2 bf16 -----------
__global__ __launch_bounds__(256) void resid_ln_f32(
    const float* __restrict__ X, const float* __restrict__ P,
    const float* __restrict__ G, const float* __restrict__ Bt,
    float* __restrict__ CLS, u16* __restrict__ H2) {
  __shared__ float red[4];
  int row = blockIdx.x, t = threadIdx.x;
  int bi = (row < 128) ? (row >> 4) : (row - 128);
  float4 xv = *(const float4*)(X + (size_t)bi * 1024 + t * 4);
  float4 pv = *(const float4*)(P + (size_t)row * 1024 + t * 4);
  float v[4] = {xv.x + pv.x, xv.y + pv.y, xv.z + pv.z, xv.w + pv.w};
  float* cp = CLS + (size_t)row * 1024 + t * 4;
#pragma unroll
  for (int i = 0; i < 4; ++i) cp[i] = v[i];
  float s = v[0] + v[1] + v[2] + v[3];
  s = block_sum4(s, red, t);
  float mean = s * (1.f / 1024.f);
  float q = 0.f;
#pragma unroll
  for (int i = 0; i < 4; ++i) { float d = v[i] - mean; q += d * d; }
  q = block_sum4(q, red, t);
  float rstd = rsqrtf(q * (1.f / 1024.f) + 1e-5f);
  float4 g = *(const float4*)(G + t * 4);
  float4 b = *(const float4*)(Bt + t * 4);
  float gg[4] = {g.x, g.y, g.z, g.w}, bb[4] = {b.x, b.y, b.z, b.w};
  u16 o[4];
#pragma unroll
  for (int i = 0; i < 4; ++i) o[i] = f2bf((v[i] - mean) * rstd * gg[i] + bb[i]);
  u32* op = (u32*)(H2 + (size_t)row * 1024 + t * 4);
  op[0] = (u32)o[0] | ((u32)o[1] << 16);
  op[1] = (u32)o[2] | ((u32)o[3] << 16);
}

// ------ m97-style 128x128 tile GEMM: C = A @ W^T + bias(fp32), out bf16 -----
__global__ __launch_bounds__(256) void gemm_bt_128(
    const u16* __restrict__ A, int lda, const u16* __restrict__ W, int ldw,
    const float* __restrict__ bias, u16* __restrict__ C, int ldc,
    int M, int N, int K) {
  __shared__ u16 As[128 * 64];
  __shared__ u16 Bs[128 * 64];
  int t = threadIdx.x, lane = t & 63, wv = t >> 6;
  int bm = blockIdx.x * 128, bn = blockIdx.y * 128;
  int quad = lane >> 4, rlow = lane & 15;
  int lrow = lane >> 3, lcol = (lane & 7) * 8;
  int wrow = (wv & 1) * 64, wcol = (wv >> 1) * 64;
  f32x4 acc[4][4] = {};

  for (int k0 = 0; k0 < K; k0 += 64) {
    __syncthreads();
#pragma unroll
    for (int j = 0; j < 4; ++j) {
      int rb = j * 4 + wv;            // row-block 0..15, 8 rows each
      int row = rb * 8 + lrow;
      int gm = bm + row; if (gm >= M) gm = M - 1;   // clamp: dup rows, never stored
      GLD16(A + (size_t)gm * lda + k0 + lcol, &As[rb * 8 * 64]);
      int gn = bn + row; if (gn >= N) gn = N - 1;
      GLD16(W + (size_t)gn * ldw + k0 + lcol, &Bs[rb * 8 * 64]);
    }
    __syncthreads();
#pragma unroll
    for (int kk = 0; kk < 64; kk += 32) {
      bf16x8 a[4], b[4];
#pragma unroll
      for (int i = 0; i < 4; ++i)
        a[i] = *(const bf16x8*)(&As[(wrow + i * 16 + rlow) * 64 + kk + quad * 8]);
#pragma unroll
      for (int j = 0; j < 4; ++j)
        b[j] = *(const bf16x8*)(&Bs[(wcol + j * 16 + rlow) * 64 + kk + quad * 8]);
#pragma unroll
      for (int i = 0; i < 4; ++i)
#pragma unroll
        for (int j = 0; j < 4; ++j)
          acc[i][j] = __builtin_amdgcn_mfma_f32_16x16x32_bf16(a[i], b[j], acc[i][j], 0, 0, 0);
    }
  }
#pragma unroll
  for (int j = 0; j < 4; ++j) {
    int gn = bn + wcol + j * 16 + rlow;
    float bv = (gn < N) ? bias[gn] : 0.f;
#pragma unroll
    for (int i = 0; i < 4; ++i)
#pragma unroll
      for (int r = 0; r < 4; ++r) {
        int gm = bm + wrow + i * 16 + quad * 4 + r;
        if (gm < M && gn < N) C[(size_t)gm * ldc + gn] = f2bf(acc[i][j][r] + bv);
      }
  }
}

// ---- split-K partial: ACC[m,n] += sum over K-slice of A[m,k]*W[n,k] --------
#define LDT 72
__global__ __launch_bounds__(256) void gemm_bt_splitk(
    const u16* __restrict__ A, int lda, const u16* __restrict__ W, int ldw,
    float* __restrict__ ACC, int ldc, int M, int N, int KC) {
  __shared__ u16 As[64 * LDT];
  __shared__ u16 Bs[64 * LDT];
  int t = threadIdx.x;
  int bm = blockIdx.x * 64, bn = blockIdx.y * 64;
  int kbase = blockIdx.z * KC;
  int lane = t & 63, wv = t >> 6;
  f32x4 acc[4] = {};
  int srow = t >> 3;
  int scol = (t & 7) * 8;

  for (int k0 = kbase; k0 < kbase + KC; k0 += 64) {
    __syncthreads();
#pragma unroll
    for (int rr = 0; rr < 2; ++rr) {
      int r = srow + rr * 32;
      int gm = bm + r;
      uint4 da = {0, 0, 0, 0};
      if (gm < M) da = *(const uint4*)(A + (size_t)gm * lda + k0 + scol);
      *(uint4*)(&As[r * LDT + scol]) = da;
      int gn = bn + r;
      uint4 dw = {0, 0, 0, 0};
      if (gn < N) dw = *(const uint4*)(W + (size_t)gn * ldw + k0 + scol);
      *(uint4*)(&Bs[r * LDT + scol]) = dw;
    }
    __syncthreads();
    int quad = lane >> 4, rlow = lane & 15;
#pragma unroll
    for (int kk = 0; kk < 64; kk += 32) {
      bf16x8 a = *(const bf16x8*)(&As[(wv * 16 + rlow) * LDT + kk + quad * 8]);
#pragma unroll
      for (int j = 0; j < 4; ++j) {
        bf16x8 b = *(const bf16x8*)(&Bs[(j * 16 + rlow) * LDT + kk + quad * 8]);
        acc[j] = __builtin_amdgcn_mfma_f32_16x16x32_bf16(a, b, acc[j], 0, 0, 0);
      }
    }
  }
  int quad = lane >> 4, cidx = lane & 15;
#pragma unroll
  for (int j = 0; j < 4; ++j) {
    int gn = bn + j * 16 + cidx;
#pragma unroll
    for (int r = 0; r < 4; ++r) {
      int gm = bm + wv * 16 + quad * 4 + r;
      if (gm < M && gn < N) atomicAdd(&ACC[(size_t)gm * ldc + gn], acc[j][r]);
    }
  }
}

// ---------------- ACC[m,n] = bias[n] (fp32 bias) ----------------------------
__global__ __launch_bounds__(256) void acc_init(
    float* __restrict__ ACC, const float* __restrict__ bias, int nmask, int total) {
  int i = (blockIdx.x * 256 + threadIdx.x) * 4;
  if (i < total) {
#pragma unroll
    for (int k = 0; k < 4; ++k) ACC[i + k] = bias[(i + k) & nmask];
  }
}

// ---------------- QuickGELU on fp32 acc -> bf16 ------------------------------
__global__ __launch_bounds__(256) void gelu_cvt(
    const float* __restrict__ ACC, u16* __restrict__ O, int total) {
  int i = (blockIdx.x * 256 + threadIdx.x) * 4;
  if (i < total) {
#pragma unroll
    for (int k = 0; k < 4; ++k) {
      float v = ACC[i + k];
      O[i + k] = f2bf(v / (1.f + __expf(-1.702f * v)));
    }
  }
}

// ---------------- out(fp32) = accP + clspre ---------------------------------
__global__ __launch_bounds__(256) void final_out(
    const float* __restrict__ ACC, const float* __restrict__ CLS,
    float* __restrict__ O, int total) {
  int i = (blockIdx.x * 256 + threadIdx.x) * 4;
  if (i < total) {
#pragma unroll
    for (int k = 0; k < 4; ++k) O[i + k] = ACC[i + k] + CLS[i + k];
  }
}

// --- qw[b,h,:] = sum_n (q0[b,h*64+n]/8)*Wk[h*64+n,:]; c0 = qs . bk ----------
__global__ __launch_bounds__(256) void qw_build(
    const float* __restrict__ Q0, const float* __restrict__ WK,
    const float* __restrict__ BK, u16* __restrict__ QW, float* __restrict__ C0) {
  int bh = blockIdx.x, b = bh >> 4, h = bh & 15;
  __shared__ float qs[64];
  int t = threadIdx.x;
  if (t < 64) qs[t] = Q0[b * 1024 + h * 64 + t] * 0.125f;
  __syncthreads();
  float acc[4] = {0.f, 0.f, 0.f, 0.f};
  int d0 = t * 4;
#pragma unroll 4
  for (int n = 0; n < 64; ++n) {
    float4 w = *(const float4*)(WK + (size_t)(h * 64 + n) * 1024 + d0);
    float q = qs[n];
    acc[0] += q * w.x;
    acc[1] += q * w.y;
    acc[2] += q * w.z;
    acc[3] += q * w.w;
  }
  u16 o[4];
#pragma unroll
  for (int i = 0; i < 4; ++i) o[i] = f2bf(acc[i]);
  u32* op = (u32*)(QW + (size_t)bh * 1024 + d0);
  op[0] = (u32)o[0] | ((u32)o[1] << 16);
  op[1] = (u32)o[2] | ((u32)o[3] << 16);
  if (t == 0) {
    float c = 0.f;
    for (int n = 0; n < 64; ++n) c += qs[n] * BK[h * 64 + n];
    C0[bh] = c;
  }
}

// ------ attn[b,h,s] = h[s,b,:] . qw[b,h,:] + c0[b,h]  (bf16 in, fp32 out) ---
#define HLD 516
__global__ __launch_bounds__(256) void attn_dot(
    const u16* __restrict__ H, const u16* __restrict__ QW,
    const float* __restrict__ C0, float* __restrict__ ATT) {
  __shared__ u32 Hs[16 * HLD];
  int b = blockIdx.y, s0 = blockIdx.x * 16, t = threadIdx.x;
  for (int idx = t; idx < 16 * 512; idx += 256) {
    int row = idx >> 9, col = idx & 511;
    int s = s0 + row;
    u32 v = 0;
    if (s < 577) v = *(const u32*)(H + ((size_t)(s * 8 + b) << 10) + col * 2);
    Hs[row * HLD + col] = v;
  }
  __syncthreads();
  int si = t & 15, hh = t >> 4;
  int s = s0 + si;
  if (s < 577) {
    const u32* hr = &Hs[si * HLD];
    const u32* qr = (const u32*)(QW + (size_t)(b * 16 + hh) * 1024);
    float acc = 0.f;
    for (int d = 0; d < 512; d += 4) {
      uint4 hv = *(const uint4*)(&hr[d]);
      uint4 qv = *(const uint4*)(&qr[d]);
      acc += bf2f(hv.x & 0xffff) * bf2f(qv.x & 0xffff) + bf2f(hv.x >> 16) * bf2f(qv.x >> 16);
      acc += bf2f(hv.y & 0xffff) * bf2f(qv.y & 0xffff) + bf2f(hv.y >> 16) * bf2f(qv.y >> 16);
      acc += bf2f(hv.z & 0xffff) * bf2f(qv.z & 0xffff) + bf2f(hv.z >> 16) * bf2f(qv.z >> 16);
      acc += bf2f(hv.w & 0xffff) * bf2f(qv.w & 0xffff) + bf2f(hv.w >> 16) * bf2f(qv.w >> 16);
    }
    ATT[(size_t)(b * 16 + hh) * 577 + s] = acc + C0[b * 16 + hh];
  }
}

// ---- softmax(attn [+mask fp32]) then PV over bf16 V ------------------------
__global__ __launch_bounds__(256) void softmax_pv(
    const float* __restrict__ ATT, const float* __restrict__ MASK,
    const u16* __restrict__ V, u16* __restrict__ AO) {
  const int S = 577;
  int blk = blockIdx.x;
  int b = blk / 272, rem = blk % 272;
  int x = rem >> 4, h = rem & 15;
  __shared__ float p[S];
  __shared__ float redm[4];
  __shared__ float reds[4];
  __shared__ float partial[256];
  int t = threadIdx.x, lane = t & 63, wv = t >> 6;
  const float* arow = ATT + (size_t)(b * 16 + h) * S;
  float lmax = -3e38f;
  for (int s = t; s < S; s += 256) {
    float v = arow[s];
    if (x < 16) v += MASK[(size_t)((b * 16 + x) * 16 + h) * S + s];
    p[s] = v;
    lmax = fmaxf(lmax, v);
  }
#pragma unroll
  for (int o = 32; o; o >>= 1) lmax = fmaxf(lmax, __shfl_xor(lmax, o, 64));
  if (lane == 0) redm[wv] = lmax;
  __syncthreads();
  float m = fmaxf(fmaxf(redm[0], redm[1]), fmaxf(redm[2], redm[3]));
  float lsum = 0.f;
  for (int s = t; s < S; s += 256) {
    float e = __expf(p[s] - m);
    p[s] = e;
    lsum += e;
  }
#pragma unroll
  for (int o = 32; o; o >>= 1) lsum += __shfl_xor(lsum, o, 64);
  if (lane == 0) reds[wv] = lsum;
  __syncthreads();
  float inv = 1.f / (reds[0] + reds[1] + reds[2] + reds[3]);
  // PV: unroll x8 so 8 independent V loads are in flight per wave
  float acc = 0.f;
  const u16* vb = V + h * 64 + lane;
  int s = wv;
  for (; s + 28 < S; s += 32) {
    float w0 = p[s], w1 = p[s + 4], w2 = p[s + 8], w3 = p[s + 12];
    float w4 = p[s + 16], w5 = p[s + 20], w6 = p[s + 24], w7 = p[s + 28];
    float v0 = bf2f(vb[(size_t)((s)*8 + b) << 10]);
    float v1 = bf2f(vb[(size_t)((s + 4) * 8 + b) << 10]);
    float v2 = bf2f(vb[(size_t)((s + 8) * 8 + b) << 10]);
    float v3 = bf2f(vb[(size_t)((s + 12) * 8 + b) << 10]);
    float v4 = bf2f(vb[(size_t)((s + 16) * 8 + b) << 10]);
    float v5 = bf2f(vb[(size_t)((s + 20) * 8 + b) << 10]);
    float v6 = bf2f(vb[(size_t)((s + 24) * 8 + b) << 10]);
    float v7 = bf2f(vb[(size_t)((s + 28) * 8 + b) << 10]);
    acc += w0 * v0 + w1 * v1 + w2 * v2 + w3 * v3;
    acc += w4 * v4 + w5 * v5 + w6 * v6 + w7 * v7;
  }
  for (; s < S; s += 4) acc += p[s] * bf2f(vb[(size_t)(s * 8 + b) << 10]);
  partial[t] = acc;
  __syncthreads();
  if (t < 64) {
    float r = (partial[t] + partial[t + 64] + partial[t + 128] + partial[t + 192]) * inv;
    int row = (x < 16) ? (b * 16 + x) : (128 + b);
    AO[(size_t)row * 1024 + h * 64 + t] = f2bf(r);
  }
}

// ----------------------------------------------------------------------------
extern "C" void kernel_launch(void* const* d_in, const int* in_sizes, int n_in,
                              void* d_out, int out_size, void* d_ws, size_t ws_size,
                              hipStream_t stream) {
  const float* x      = (const float*)d_in[0];
  const float* mask   = (const float*)d_in[1];
  const float* in_w   = (const float*)d_in[5];
  const float* in_b   = (const float*)d_in[6];
  const float* out_w  = (const float*)d_in[7];
  const float* out_b  = (const float*)d_in[8];
  const float* ln1_g  = (const float*)d_in[9];
  const float* ln1_b  = (const float*)d_in[10];
  const float* ln2_g  = (const float*)d_in[11];
  const float* ln2_b  = (const float*)d_in[12];
  const float* fc_w   = (const float*)d_in[13];
  const float* fc_b   = (const float*)d_in[14];
  const float* proj_w = (const float*)d_in[15];
  const float* proj_b = (const float*)d_in[16];
  float* out = (float*)d_out;

  const int SB = 577 * 8;  // 4616
  char* base = (char*)d_ws;
  size_t off = 0;
  auto alloc = [&](size_t bytes) {
    char* p = base + off;
    off += (bytes + 255) & ~(size_t)255;
    return p;
  };
  // bf16 weight copies (MFMA operands)
  u16* wqkv_b  = (u16*)alloc((size_t)3072 * 1024 * 2);  // q|k|v rows
  u16* wout_b  = (u16*)alloc((size_t)1024 * 1024 * 2);
  u16* wfc_b   = (u16*)alloc((size_t)4096 * 1024 * 2);
  u16* wproj_b = (u16*)alloc((size_t)4096 * 1024 * 2);
  // activations / accumulators
  u16* h        = (u16*)alloc((size_t)SB * 1024 * 2);
  u16* v        = (u16*)alloc((size_t)SB * 1024 * 2);
  float* accQ   = (float*)alloc(8 * 1024 * 4);
  u16* qw       = (u16*)alloc(128 * 1024 * 2);
  float* c0     = (float*)alloc(128 * 4);
  float* attn   = (float*)alloc(128 * 577 * 4);
  u16* attn_out = (u16*)alloc(136 * 1024 * 2);
  float* accO   = (float*)alloc(136 * 1024 * 4);
  float* clspre = (float*)alloc(136 * 1024 * 4);
  u16* h2       = (u16*)alloc(136 * 1024 * 2);
  float* accF   = (float*)alloc((size_t)136 * 4096 * 4);
  u16* hg       = (u16*)alloc((size_t)136 * 4096 * 2);
  float* accP   = (float*)alloc(136 * 1024 * 4);
  // total ~44.6 MB; ws_size >= ~58.6 MB (established round 2/6)

  // 0) weights -> bf16
  cvt_f32_bf16<<<3072, 256, 0, stream>>>(in_w, wqkv_b, 3072 * 1024);
  cvt_f32_bf16<<<1024, 256, 0, stream>>>(out_w, wout_b, 1024 * 1024);
  cvt_f32_bf16<<<4096, 256, 0, stream>>>(fc_w, wfc_b, 4096 * 1024);
  cvt_f32_bf16<<<4096, 256, 0, stream>>>(proj_w, wproj_b, 4096 * 1024);

  // 1) LN1 over all S*B rows (fp32 in, bf16 out)
  ln_rows_f32<<<SB, 256, 0, stream>>>(x, ln1_g, ln1_b, h);
  // 2) v = h @ Wv^T + bv  (m97 128-tile, global_load_lds w=16)
  gemm_bt_128<<<dim3(37, 8), 256, 0, stream>>>(
      h, 1024, wqkv_b + (size_t)2048 * 1024, 1024, in_b + 2048, v, 1024,
      SB, 1024, 1024);
  // 3) q0(fp32) = h[rows 0..7] @ Wq^T + bq  via split-K
  acc_init<<<8, 256, 0, stream>>>(accQ, in_b, 1023, 8 * 1024);
  gemm_bt_splitk<<<dim3(1, 16, 8), 256, 0, stream>>>(
      h, 1024, wqkv_b, 1024, accQ, 1024, 8, 1024, 128);
  // 4) qw = (q0/8) . Wk  (raw fp32 Wk, bk)
  qw_build<<<128, 256, 0, stream>>>(accQ, in_w + (size_t)1024 * 1024,
                                    in_b + 1024, qw, c0);
  // 5) attn logits
  attn_dot<<<dim3(37, 8), 256, 0, stream>>>(h, qw, c0, attn);
  // 6) softmax(+mask) + PV
  softmax_pv<<<8 * 17 * 16, 256, 0, stream>>>(attn, mask, v, attn_out);
  // 7) out-proj via split-K
  acc_init<<<136, 256, 0, stream>>>(accO, out_b, 1023, 136 * 1024);
  gemm_bt_splitk<<<dim3(3, 16, 8), 256, 0, stream>>>(
      attn_out, 1024, wout_b, 1024, accO, 1024, 136, 1024, 128);
  // 8) residual + LN2
  resid_ln_f32<<<136, 256, 0, stream>>>(x, accO, ln2_g, ln2_b, clspre, h2);
  // 9) fc via split-K, then QuickGELU
  acc_init<<<544, 256, 0, stream>>>(accF, fc_b, 4095, 136 * 4096);
  gemm_bt_splitk<<<dim3(3, 64, 4), 256, 0, stream>>>(
      h2, 1024, wfc_b, 1024, accF, 4096, 136, 4096, 256);
  gelu_cvt<<<544, 256, 0, stream>>>(accF, hg, 136 * 4096);
  // 10) proj via split-K, then +clspre -> d_out (fp32)
  acc_init<<<136, 256, 0, stream>>>(accP, proj_b, 1023, 136 * 1024);
  gemm_bt_splitk<<<dim3(3, 16, 16), 256, 0, stream>>>(
      hg, 4096, wproj_b, 4096, accP, 1024, 136, 1024, 256);
  final_out<<<136, 256, 0, stream>>>(accP, clspre, out, 136 * 1024);

  (void)in_sizes; (void)n_in; (void)out_size; (void)ws_size;
}

// Round 8
// 267.633 us; speedup vs baseline: 1.8220x; 1.0561x over previous
//
#include <hip/hip_runtime.h>
#include <stdint.h>

typedef unsigned short u16;
typedef unsigned int u32;
typedef __bf16 bf16x8 __attribute__((ext_vector_type(8)));
typedef float f32x4 __attribute__((ext_vector_type(4)));

// ---------- bf16 helpers ----------
__device__ __forceinline__ float bf2f(u16 u) {
  u32 v = ((u32)u) << 16;
  return __builtin_bit_cast(float, v);
}
__device__ __forceinline__ u16 f2bf(float f) {
  u32 u = __builtin_bit_cast(u32, f);
  u32 r = u + 0x7fffu + ((u >> 16) & 1u);
  return (u16)(r >> 16);
}

__device__ __forceinline__ float block_sum4(float v, float* red, int t) {
#pragma unroll
  for (int o = 32; o; o >>= 1) v += __shfl_xor(v, o, 64);
  if ((t & 63) == 0) red[t >> 6] = v;
  __syncthreads();
  float r = red[0] + red[1] + red[2] + red[3];
  __syncthreads();
  return r;
}

// async global->LDS, 16B per lane; LDS dest = wave-uniform base + lane*16
#define GLD16(gp, lp)                                                   \
  __builtin_amdgcn_global_load_lds(                                     \
      (const __attribute__((address_space(1))) void*)(gp),              \
      (__attribute__((address_space(3))) void*)(lp), 16, 0, 0)

// ------ fused fp32->bf16 conversion over 5 weight segments, one launch ------
struct CvtSegs {
  const float* src[5];
  u16* dst[5];
  int nblk[6];  // exclusive prefix of block counts, nblk[5] = total
};
__global__ __launch_bounds__(256) void cvt_all(CvtSegs segs) {
  int blk = blockIdx.x;
  int s = 0;
  while (s < 4 && blk >= segs.nblk[s + 1]) ++s;
  int i = (blk - segs.nblk[s]) * 1024 + threadIdx.x * 4;
  float4 f = *(const float4*)(segs.src[s] + i);
  u32 lo = (u32)f2bf(f.x) | ((u32)f2bf(f.y) << 16);
  u32 hi = (u32)f2bf(f.z) | ((u32)f2bf(f.w) << 16);
  uint2 val = {lo, hi};
  *(uint2*)(segs.dst[s] + i) = val;
}

// ---------------- LayerNorm over fp32 rows (D=1024), out bf16 ----------------
__global__ __launch_bounds__(256) void ln_rows_f32(
    const float* __restrict__ X, const float* __restrict__ G,
    const float* __restrict__ Bt, u16* __restrict__ O) {
  __shared__ float red[4];
  int row = blockIdx.x, t = threadIdx.x;
  float4 xv = *(const float4*)(X + (size_t)row * 1024 + t * 4);
  float v[4] = {xv.x, xv.y, xv.z, xv.w};
  float s = v[0] + v[1] + v[2] + v[3];
  s = block_sum4(s, red, t);
  float mean = s * (1.f / 1024.f);
  float q = 0.f;
#pragma unroll
  for (int i = 0; i < 4; ++i) { float d = v[i] - mean; q += d * d; }
  q = block_sum4(q, red, t);
  float rstd = rsqrtf(q * (1.f / 1024.f) + 1e-5f);
  float4 g = *(const float4*)(G + t * 4);
  float4 b = *(const float4*)(Bt + t * 4);
  float gg[4] = {g.x, g.y, g.z, g.w}, bb[4] = {b.x, b.y, b.z, b.w};
  u16 o[4];
#pragma unroll
  for (int i = 0; i < 4; ++i) o[i] = f2bf((v[i] - mean) * rstd * gg[i] + bb[i]);
  u32* op = (u32*)(O + (size_t)row * 1024 + t * 4);
  op[0] = (u32)o[0] | ((u32)o[1] << 16);
  op[1] = (u32)o[2] | ((u32)o[3] << 16);
}

// ---- reduce 8 out-proj partials(+bias) + x0 residual + LN2 ------------------
__global__ __launch_bounds__(256) void resid_ln_red(
    const float* __restrict__ X, const float* __restrict__ OP,  // 8 partials
    const float* __restrict__ OB, const float* __restrict__ G,
    const float* __restrict__ Bt, float* __restrict__ CLS, u16* __restrict__ H2) {
  __shared__ float red[4];
  const int PS = 136 * 1024;
  int row = blockIdx.x, t = threadIdx.x;
  int bi = (row < 128) ? (row >> 4) : (row - 128);
  float4 xv = *(const float4*)(X + (size_t)bi * 1024 + t * 4);
  float4 ob = *(const float4*)(OB + t * 4);
  float v[4] = {xv.x + ob.x, xv.y + ob.y, xv.z + ob.z, xv.w + ob.w};
#pragma unroll
  for (int z = 0; z < 8; ++z) {
    float4 pv = *(const float4*)(OP + (size_t)z * PS + (size_t)row * 1024 + t * 4);
    v[0] += pv.x; v[1] += pv.y; v[2] += pv.z; v[3] += pv.w;
  }
  float* cp = CLS + (size_t)row * 1024 + t * 4;
#pragma unroll
  for (int i = 0; i < 4; ++i) cp[i] = v[i];
  float s = v[0] + v[1] + v[2] + v[3];
  s = block_sum4(s, red, t);
  float mean = s * (1.f / 1024.f);
  float q = 0.f;
#pragma unroll
  for (int i = 0; i < 4; ++i) { float d = v[i] - mean; q += d * d; }
  q = block_sum4(q, red, t);
  float rstd = rsqrtf(q * (1.f / 1024.f) + 1e-5f);
  float4 g = *(const float4*)(G + t * 4);
  float4 b = *(const float4*)(Bt + t * 4);
  float gg[4] = {g.x, g.y, g.z, g.w}, bb[4] = {b.x, b.y, b.z, b.w};
  u16 o[4];
#pragma unroll
  for (int i = 0; i < 4; ++i) o[i] = f2bf((v[i] - mean) * rstd * gg[i] + bb[i]);
  u32* op = (u32*)(H2 + (size_t)row * 1024 + t * 4);
  op[0] = (u32)o[0] | ((u32)o[1] << 16);
  op[1] = (u32)o[2] | ((u32)o[3] << 16);
}

// ------ m97-style 128x128 tile GEMM: C = A @ W^T + bias(fp32), out bf16 -----
__global__ __launch_bounds__(256) void gemm_bt_128(
    const u16* __restrict__ A, int lda, const u16* __restrict__ W, int ldw,
    const float* __restrict__ bias, u16* __restrict__ C, int ldc,
    int M, int N, int K) {
  __shared__ u16 As[128 * 64];
  __shared__ u16 Bs[128 * 64];
  int t = threadIdx.x, lane = t & 63, wv = t >> 6;
  int bm = blockIdx.x * 128, bn = blockIdx.y * 128;
  int quad = lane >> 4, rlow = lane & 15;
  int lrow = lane >> 3, lcol = (lane & 7) * 8;
  int wrow = (wv & 1) * 64, wcol = (wv >> 1) * 64;
  f32x4 acc[4][4] = {};

  for (int k0 = 0; k0 < K; k0 += 64) {
    __syncthreads();
#pragma unroll
    for (int j = 0; j < 4; ++j) {
      int rb = j * 4 + wv;
      int row = rb * 8 + lrow;
      int gm = bm + row; if (gm >= M) gm = M - 1;
      GLD16(A + (size_t)gm * lda + k0 + lcol, &As[rb * 8 * 64]);
      int gn = bn + row; if (gn >= N) gn = N - 1;
      GLD16(W + (size_t)gn * ldw + k0 + lcol, &Bs[rb * 8 * 64]);
    }
    __syncthreads();
#pragma unroll
    for (int kk = 0; kk < 64; kk += 32) {
      bf16x8 a[4], b[4];
#pragma unroll
      for (int i = 0; i < 4; ++i)
        a[i] = *(const bf16x8*)(&As[(wrow + i * 16 + rlow) * 64 + kk + quad * 8]);
#pragma unroll
      for (int j = 0; j < 4; ++j)
        b[j] = *(const bf16x8*)(&Bs[(wcol + j * 16 + rlow) * 64 + kk + quad * 8]);
#pragma unroll
      for (int i = 0; i < 4; ++i)
#pragma unroll
        for (int j = 0; j < 4; ++j)
          acc[i][j] = __builtin_amdgcn_mfma_f32_16x16x32_bf16(a[i], b[j], acc[i][j], 0, 0, 0);
    }
  }
#pragma unroll
  for (int j = 0; j < 4; ++j) {
    int gn = bn + wcol + j * 16 + rlow;
    float bv = (gn < N) ? bias[gn] : 0.f;
#pragma unroll
    for (int i = 0; i < 4; ++i)
#pragma unroll
      for (int r = 0; r < 4; ++r) {
        int gm = bm + wrow + i * 16 + quad * 4 + r;
        if (gm < M && gn < N) C[(size_t)gm * ldc + gn] = f2bf(acc[i][j][r] + bv);
      }
  }
}

// ---- split-K partials: P[z][m,n] = sum over K-slice z (plain stores) -------
#define LDT 72
__global__ __launch_bounds__(256) void gemm_bt_splitk_p(
    const u16* __restrict__ A, int lda, const u16* __restrict__ W, int ldw,
    float* __restrict__ P, int pstride, int ldc, int M, int N, int KC) {
  __shared__ u16 As[64 * LDT];
  __shared__ u16 Bs[64 * LDT];
  int t = threadIdx.x;
  int bm = blockIdx.x * 64, bn = blockIdx.y * 64;
  int kbase = blockIdx.z * KC;
  float* PZ = P + (size_t)blockIdx.z * pstride;
  int lane = t & 63, wv = t >> 6;
  f32x4 acc[4] = {};
  int srow = t >> 3;
  int scol = (t & 7) * 8;

  for (int k0 = kbase; k0 < kbase + KC; k0 += 64) {
    __syncthreads();
#pragma unroll
    for (int rr = 0; rr < 2; ++rr) {
      int r = srow + rr * 32;
      int gm = bm + r;
      uint4 da = {0, 0, 0, 0};
      if (gm < M) da = *(const uint4*)(A + (size_t)gm * lda + k0 + scol);
      *(uint4*)(&As[r * LDT + scol]) = da;
      int gn = bn + r;
      uint4 dw = {0, 0, 0, 0};
      if (gn < N) dw = *(const uint4*)(W + (size_t)gn * ldw + k0 + scol);
      *(uint4*)(&Bs[r * LDT + scol]) = dw;
    }
    __syncthreads();
    int quad = lane >> 4, rlow = lane & 15;
#pragma unroll
    for (int kk = 0; kk < 64; kk += 32) {
      bf16x8 a = *(const bf16x8*)(&As[(wv * 16 + rlow) * LDT + kk + quad * 8]);
#pragma unroll
      for (int j = 0; j < 4; ++j) {
        bf16x8 b = *(const bf16x8*)(&Bs[(j * 16 + rlow) * LDT + kk + quad * 8]);
        acc[j] = __builtin_amdgcn_mfma_f32_16x16x32_bf16(a, b, acc[j], 0, 0, 0);
      }
    }
  }
  int quad = lane >> 4, cidx = lane & 15;
#pragma unroll
  for (int j = 0; j < 4; ++j) {
    int gn = bn + j * 16 + cidx;
#pragma unroll
    for (int r = 0; r < 4; ++r) {
      int gm = bm + wv * 16 + quad * 4 + r;
      if (gm < M && gn < N) PZ[(size_t)gm * ldc + gn] = acc[j][r];
    }
  }
}

// ---- reduce 4 fc partials + bias, QuickGELU -> bf16 ------------------------
__global__ __launch_bounds__(256) void gelu_red(
    const float* __restrict__ FP, const float* __restrict__ FB,
    u16* __restrict__ O, int total) {
  const int PS = 136 * 4096;
  int i = (blockIdx.x * 256 + threadIdx.x) * 4;
  if (i < total) {
#pragma unroll
    for (int k = 0; k < 4; ++k) {
      int idx = i + k;
      float v = FB[idx & 4095];
#pragma unroll
      for (int z = 0; z < 4; ++z) v += FP[(size_t)z * PS + idx];
      O[idx] = f2bf(v / (1.f + __expf(-1.702f * v)));
    }
  }
}

// ---- reduce 16 proj partials + bias + clspre -> fp32 out -------------------
__global__ __launch_bounds__(256) void final_red(
    const float* __restrict__ PP, const float* __restrict__ PB,
    const float* __restrict__ CLS, float* __restrict__ O, int total) {
  const int PS = 136 * 1024;
  int i = (blockIdx.x * 256 + threadIdx.x) * 4;
  if (i < total) {
#pragma unroll
    for (int k = 0; k < 4; ++k) {
      int idx = i + k;
      float v = PB[idx & 1023] + CLS[idx];
#pragma unroll
      for (int z = 0; z < 16; ++z) v += PP[(size_t)z * PS + idx];
      O[idx] = v;
    }
  }
}

// --- qw_build with q0-partials reduce: qs = (sum_z Qp + bq)*0.125 -----------
__global__ __launch_bounds__(256) void qw_build(
    const float* __restrict__ QP, const float* __restrict__ QB,
    const float* __restrict__ WK, const float* __restrict__ BK,
    u16* __restrict__ QW, float* __restrict__ C0) {
  const int PS = 8 * 1024;
  int bh = blockIdx.x, b = bh >> 4, h = bh & 15;
  __shared__ float qs[64];
  int t = threadIdx.x;
  if (t < 64) {
    int n = h * 64 + t;
    float q = QB[n];
#pragma unroll
    for (int z = 0; z < 8; ++z) q += QP[(size_t)z * PS + b * 1024 + n];
    qs[t] = q * 0.125f;
  }
  __syncthreads();
  float acc[4] = {0.f, 0.f, 0.f, 0.f};
  int d0 = t * 4;
#pragma unroll 4
  for (int n = 0; n < 64; ++n) {
    float4 w = *(const float4*)(WK + (size_t)(h * 64 + n) * 1024 + d0);
    float q = qs[n];
    acc[0] += q * w.x;
    acc[1] += q * w.y;
    acc[2] += q * w.z;
    acc[3] += q * w.w;
  }
  u16 o[4];
#pragma unroll
  for (int i = 0; i < 4; ++i) o[i] = f2bf(acc[i]);
  u32* op = (u32*)(QW + (size_t)bh * 1024 + d0);
  op[0] = (u32)o[0] | ((u32)o[1] << 16);
  op[1] = (u32)o[2] | ((u32)o[3] << 16);
  if (t == 0) {
    float c = 0.f;
    for (int n = 0; n < 64; ++n) c += qs[n] * BK[h * 64 + n];
    C0[bh] = c;
  }
}

// ------ attn[b,h,s] = h[s,b,:] . qw[b,h,:] + c0[b,h]  (bf16 in, fp32 out) ---
#define HLD 516
__global__ __launch_bounds__(256) void attn_dot(
    const u16* __restrict__ H, const u16* __restrict__ QW,
    const float* __restrict__ C0, float* __restrict__ ATT) {
  __shared__ u32 Hs[16 * HLD];
  int b = blockIdx.y, s0 = blockIdx.x * 16, t = threadIdx.x;
  for (int idx = t; idx < 16 * 512; idx += 256) {
    int row = idx >> 9, col = idx & 511;
    int s = s0 + row;
    u32 v = 0;
    if (s < 577) v = *(const u32*)(H + ((size_t)(s * 8 + b) << 10) + col * 2);
    Hs[row * HLD + col] = v;
  }
  __syncthreads();
  int si = t & 15, hh = t >> 4;
  int s = s0 + si;
  if (s < 577) {
    const u32* hr = &Hs[si * HLD];
    const u32* qr = (const u32*)(QW + (size_t)(b * 16 + hh) * 1024);
    float acc = 0.f;
    for (int d = 0; d < 512; d += 4) {
      uint4 hv = *(const uint4*)(&hr[d]);
      uint4 qv = *(const uint4*)(&qr[d]);
      acc += bf2f(hv.x & 0xffff) * bf2f(qv.x & 0xffff) + bf2f(hv.x >> 16) * bf2f(qv.x >> 16);
      acc += bf2f(hv.y & 0xffff) * bf2f(qv.y & 0xffff) + bf2f(hv.y >> 16) * bf2f(qv.y >> 16);
      acc += bf2f(hv.z & 0xffff) * bf2f(qv.z & 0xffff) + bf2f(hv.z >> 16) * bf2f(qv.z >> 16);
      acc += bf2f(hv.w & 0xffff) * bf2f(qv.w & 0xffff) + bf2f(hv.w >> 16) * bf2f(qv.w >> 16);
    }
    ATT[(size_t)(b * 16 + hh) * 577 + s] = acc + C0[b * 16 + hh];
  }
}

// ---- softmax(attn [+mask fp32]) then PV over bf16 V ------------------------
__global__ __launch_bounds__(256) void softmax_pv(
    const float* __restrict__ ATT, const float* __restrict__ MASK,
    const u16* __restrict__ V, u16* __restrict__ AO) {
  const int S = 577;
  int blk = blockIdx.x;
  int b = blk / 272, rem = blk % 272;
  int x = rem >> 4, h = rem & 15;
  __shared__ float p[S];
  __shared__ float redm[4];
  __shared__ float reds[4];
  __shared__ float partial[256];
  int t = threadIdx.x, lane = t & 63, wv = t >> 6;
  const float* arow = ATT + (size_t)(b * 16 + h) * S;
  float lmax = -3e38f;
  for (int s = t; s < S; s += 256) {
    float v = arow[s];
    if (x < 16) v += MASK[(size_t)((b * 16 + x) * 16 + h) * S + s];
    p[s] = v;
    lmax = fmaxf(lmax, v);
  }
#pragma unroll
  for (int o = 32; o; o >>= 1) lmax = fmaxf(lmax, __shfl_xor(lmax, o, 64));
  if (lane == 0) redm[wv] = lmax;
  __syncthreads();
  float m = fmaxf(fmaxf(redm[0], redm[1]), fmaxf(redm[2], redm[3]));
  float lsum = 0.f;
  for (int s = t; s < S; s += 256) {
    float e = __expf(p[s] - m);
    p[s] = e;
    lsum += e;
  }
#pragma unroll
  for (int o = 32; o; o >>= 1) lsum += __shfl_xor(lsum, o, 64);
  if (lane == 0) reds[wv] = lsum;
  __syncthreads();
  float inv = 1.f / (reds[0] + reds[1] + reds[2] + reds[3]);
  float acc = 0.f;
  const u16* vb = V + h * 64 + lane;
  int s = wv;
  for (; s + 28 < S; s += 32) {
    float w0 = p[s], w1 = p[s + 4], w2 = p[s + 8], w3 = p[s + 12];
    float w4 = p[s + 16], w5 = p[s + 20], w6 = p[s + 24], w7 = p[s + 28];
    float v0 = bf2f(vb[(size_t)((s)*8 + b) << 10]);
    float v1 = bf2f(vb[(size_t)((s + 4) * 8 + b) << 10]);
    float v2 = bf2f(vb[(size_t)((s + 8) * 8 + b) << 10]);
    float v3 = bf2f(vb[(size_t)((s + 12) * 8 + b) << 10]);
    float v4 = bf2f(vb[(size_t)((s + 16) * 8 + b) << 10]);
    float v5 = bf2f(vb[(size_t)((s + 20) * 8 + b) << 10]);
    float v6 = bf2f(vb[(size_t)((s + 24) * 8 + b) << 10]);
    float v7 = bf2f(vb[(size_t)((s + 28) * 8 + b) << 10]);
    acc += w0 * v0 + w1 * v1 + w2 * v2 + w3 * v3;
    acc += w4 * v4 + w5 * v5 + w6 * v6 + w7 * v7;
  }
  for (; s < S; s += 4) acc += p[s] * bf2f(vb[(size_t)(s * 8 + b) << 10]);
  partial[t] = acc;
  __syncthreads();
  if (t < 64) {
    float r = (partial[t] + partial[t + 64] + partial[t + 128] + partial[t + 192]) * inv;
    int row = (x < 16) ? (b * 16 + x) : (128 + b);
    AO[(size_t)row * 1024 + h * 64 + t] = f2bf(r);
  }
}

// ----------------------------------------------------------------------------
extern "C" void kernel_launch(void* const* d_in, const int* in_sizes, int n_in,
                              void* d_out, int out_size, void* d_ws, size_t ws_size,
                              hipStream_t stream) {
  const float* x      = (const float*)d_in[0];
  const float* mask   = (const float*)d_in[1];
  const float* in_w   = (const float*)d_in[5];
  const float* in_b   = (const float*)d_in[6];
  const float* out_w  = (const float*)d_in[7];
  const float* out_b  = (const float*)d_in[8];
  const float* ln1_g  = (const float*)d_in[9];
  const float* ln1_b  = (const float*)d_in[10];
  const float* ln2_g  = (const float*)d_in[11];
  const float* ln2_b  = (const float*)d_in[12];
  const float* fc_w   = (const float*)d_in[13];
  const float* fc_b   = (const float*)d_in[14];
  const float* proj_w = (const float*)d_in[15];
  const float* proj_b = (const float*)d_in[16];
  float* out = (float*)d_out;

  const int SB = 577 * 8;  // 4616
  char* base = (char*)d_ws;
  size_t off = 0;
  auto alloc = [&](size_t bytes) {
    char* p = base + off;
    off += (bytes + 255) & ~(size_t)255;
    return p;
  };
  // bf16 weight copies (MFMA operands); k-rows of in_proj skipped
  u16* wq_b    = (u16*)alloc((size_t)1024 * 1024 * 2);
  u16* wv_b    = (u16*)alloc((size_t)1024 * 1024 * 2);
  u16* wout_b  = (u16*)alloc((size_t)1024 * 1024 * 2);
  u16* wfc_b   = (u16*)alloc((size_t)4096 * 1024 * 2);
  u16* wproj_b = (u16*)alloc((size_t)4096 * 1024 * 2);
  // activations / split-K partials
  u16* h        = (u16*)alloc((size_t)SB * 1024 * 2);
  u16* v        = (u16*)alloc((size_t)SB * 1024 * 2);
  float* Qp     = (float*)alloc((size_t)8 * 8 * 1024 * 4);        // q0 partials
  u16* qw       = (u16*)alloc(128 * 1024 * 2);
  float* c0     = (float*)alloc(128 * 4);
  float* attn   = (float*)alloc(128 * 577 * 4);
  u16* attn_out = (u16*)alloc(136 * 1024 * 2);
  float* Op     = (float*)alloc((size_t)8 * 136 * 1024 * 4);      // out-proj partials
  float* clspre = (float*)alloc(136 * 1024 * 4);
  u16* h2       = (u16*)alloc(136 * 1024 * 2);
  float* Fp     = (float*)alloc((size_t)4 * 136 * 4096 * 4);      // fc partials
  u16* hg       = (u16*)alloc((size_t)136 * 4096 * 2);
  float* Pp     = (float*)alloc((size_t)16 * 136 * 1024 * 4);     // proj partials
  // total ~64 MB; ws_size ~268 MB (measured via harness fill WRITE_SIZE, R7)

  // 0) all weight conversions in ONE launch (q:1024, v:1024, out:1024,
  //    fc:4096, proj:4096 row-blocks; each block = 1024 elems)
  CvtSegs segs;
  segs.src[0] = in_w;                      segs.dst[0] = wq_b;
  segs.src[1] = in_w + (size_t)2048*1024;  segs.dst[1] = wv_b;
  segs.src[2] = out_w;                     segs.dst[2] = wout_b;
  segs.src[3] = fc_w;                      segs.dst[3] = wfc_b;
  segs.src[4] = proj_w;                    segs.dst[4] = wproj_b;
  segs.nblk[0] = 0;    segs.nblk[1] = 1024; segs.nblk[2] = 2048;
  segs.nblk[3] = 3072; segs.nblk[4] = 7168; segs.nblk[5] = 11264;
  cvt_all<<<11264, 256, 0, stream>>>(segs);

  // 1) LN1 over all S*B rows
  ln_rows_f32<<<SB, 256, 0, stream>>>(x, ln1_g, ln1_b, h);
  // 2) v = h @ Wv^T + bv  (m97 128-tile, global_load_lds w=16)
  gemm_bt_128<<<dim3(37, 8), 256, 0, stream>>>(
      h, 1024, wv_b, 1024, in_b + 2048, v, 1024, SB, 1024, 1024);
  // 3) q0 partials via split-K (z=8, KC=128)
  gemm_bt_splitk_p<<<dim3(1, 16, 8), 256, 0, stream>>>(
      h, 1024, wq_b, 1024, Qp, 8 * 1024, 1024, 8, 1024, 128);
  // 4) qw = reduce(Qp)+bq, scaled, through Wk (fp32 direct)
  qw_build<<<128, 256, 0, stream>>>(Qp, in_b, in_w + (size_t)1024 * 1024,
                                    in_b + 1024, qw, c0);
  // 5) attn logits
  attn_dot<<<dim3(37, 8), 256, 0, stream>>>(h, qw, c0, attn);
  // 6) softmax(+mask) + PV
  softmax_pv<<<8 * 17 * 16, 256, 0, stream>>>(attn, mask, v, attn_out);
  // 7) out-proj partials (z=8, KC=128)
  gemm_bt_splitk_p<<<dim3(3, 16, 8), 256, 0, stream>>>(
      attn_out, 1024, wout_b, 1024, Op, 136 * 1024, 1024, 136, 1024, 128);
  // 8) reduce(Op)+out_b + x0 residual + LN2
  resid_ln_red<<<136, 256, 0, stream>>>(x, Op, out_b, ln2_g, ln2_b, clspre, h2);
  // 9) fc partials (z=4, KC=256), then reduce+bias+QuickGELU
  gemm_bt_splitk_p<<<dim3(3, 64, 4), 256, 0, stream>>>(
      h2, 1024, wfc_b, 1024, Fp, 136 * 4096, 4096, 136, 4096, 256);
  gelu_red<<<544, 256, 0, stream>>>(Fp, fc_b, hg, 136 * 4096);
  // 10) proj partials (z=16, KC=256), then reduce+bias+clspre -> d_out
  gemm_bt_splitk_p<<<dim3(3, 16, 16), 256, 0, stream>>>(
      hg, 4096, wproj_b, 4096, Pp, 136 * 1024, 1024, 136, 1024, 256);
  final_red<<<136, 256, 0, stream>>>(Pp, proj_b, clspre, out, 136 * 1024);

  (void)in_sizes; (void)n_in; (void)out_size; (void)ws_size;
}